// Round 13
// baseline (232.900 us; speedup 1.0000x reference)
//
#include <hip/hip_runtime.h>
#include <math.h>

typedef unsigned short u16;
typedef __attribute__((ext_vector_type(8))) short short8;   // 8 bf16 = 4 VGPRs
typedef __attribute__((ext_vector_type(4))) short short4v;  // 4 bf16 = 2 VGPRs
typedef __attribute__((ext_vector_type(4))) float f32x4;    // MFMA C/D frag
typedef __attribute__((ext_vector_type(4))) unsigned int uint4v;

constexpr int Bn = 4, Sn = 2048, Dn = 1024, Hn = 16;
constexpr float SCL = 0.125f * 1.44269504f;  // 1/sqrt(64) * log2(e), folded into Wq

__device__ __forceinline__ u16 f2bf(float f) {  // RNE float->bf16
  unsigned u = __float_as_uint(f);
  u += 0x7fffu + ((u >> 16) & 1u);
  return (u16)(u >> 16);
}

__device__ __forceinline__ f32x4 mfma32(short8 a, short8 b, f32x4 c) {
  return __builtin_amdgcn_mfma_f32_16x16x32_bf16(a, b, c, 0, 0, 0);
}

__device__ __forceinline__ void gl_lds16(const u16* g, u16* l) {
  __builtin_amdgcn_global_load_lds(
      (const __attribute__((address_space(1))) unsigned int*)g,
      (__attribute__((address_space(3))) unsigned int*)l, 16, 0, 0);
}

// ---------------------------------------------------------------------------
// One launch for all f32->bf16 casts. Blocks 0..8191: x. Then 1024 each for
// wq (pre-scaled by SCL), wk, wv, wo.
// ---------------------------------------------------------------------------
__global__ __launch_bounds__(256) void cast_all(
    const float4* __restrict__ x, const float4* __restrict__ wq,
    const float4* __restrict__ wk, const float4* __restrict__ wv,
    const float4* __restrict__ wo, ushort4* __restrict__ xb,
    ushort4* __restrict__ wqb, ushort4* __restrict__ wkb,
    ushort4* __restrict__ wvb, ushort4* __restrict__ wob) {
  const int blk = blockIdx.x;
  const float4* in;
  ushort4* out;
  int base;
  float s = 1.0f;
  if (blk < 8192) {
    in = x; out = xb; base = blk;
  } else if (blk < 9216) {
    in = wq; out = wqb; base = blk - 8192; s = SCL;
  } else if (blk < 10240) {
    in = wk; out = wkb; base = blk - 9216;
  } else if (blk < 11264) {
    in = wv; out = wvb; base = blk - 10240;
  } else {
    in = wo; out = wob; base = blk - 11264;
  }
  const int i = base * 256 + threadIdx.x;
  const float4 f = in[i];
  ushort4 o;
  o.x = f2bf(f.x * s); o.y = f2bf(f.y * s);
  o.z = f2bf(f.z * s); o.w = f2bf(f.w * s);
  out[i] = o;
}

// ---------------------------------------------------------------------------
// QKV GEMM: 128x128 tile, BK=64, 4 waves, m97 two-barrier structure --
// session-proven 60.6 us (R6 container; 70.0 on R12's ~13%-slower one --
// same code, container variance). 8-phase line closed (R7/R10/R11).
// LDS at kernel scope (shared by both instantiations). Swizzle cl^(row&7),
// conflict-free (counters: 0).
// MODE 0: bf16 natural; MODE 2: bf16 into vt2 = V^T tiles [hd][key]
// (64x64 per (b,h,jt)), 16B chunks XOR-swizzled by hd -- this IS the MFMA
// A-frag layout attn consumes, so attn reads it directly (no LDS staging).
// ---------------------------------------------------------------------------
template <int MODE>
__device__ __forceinline__ void gemm_body(const u16* __restrict__ A,
                                          const u16* __restrict__ W,
                                          u16* __restrict__ Cb,
                                          int bx, int by,
                                          u16* __restrict__ Asm,
                                          u16* __restrict__ Wsm) {
  const int t = threadIdx.x;
  const int w = t >> 6, l = t & 63;
  const int wy = w >> 1, wx = w & 1;
  const int q = l >> 4, r = l & 15;
  const int m0 = bx * 128, n0 = by * 128;

  f32x4 acc[4][4] = {};

  for (int k0 = 0; k0 < 1024; k0 += 64) {
    __syncthreads();
#pragma unroll
    for (int i = 0; i < 4; ++i) {
      const int c = t + i * 256;            // 16B chunk id, 0..1023
      const int row = c >> 3, cl = c & 7;   // 8 chunks per 128B row
      const int cg = cl ^ (row & 7);        // pre-swizzled global source
      gl_lds16(A + (size_t)(m0 + row) * 1024 + k0 + cg * 8, &Asm[c * 8]);
      gl_lds16(W + (size_t)(n0 + row) * 1024 + k0 + cg * 8, &Wsm[c * 8]);
    }
    __syncthreads();
#pragma unroll
    for (int kf = 0; kf < 2; ++kf) {
      short8 af[4], bf[4];
#pragma unroll
      for (int mi = 0; mi < 4; ++mi) {
        const int rowA = wy * 64 + mi * 16 + r;
        af[mi] = *(const short8*)&Asm[rowA * 64 + ((kf * 4 + q) ^ (rowA & 7)) * 8];
        const int rowB = wx * 64 + mi * 16 + r;
        bf[mi] = *(const short8*)&Wsm[rowB * 64 + ((kf * 4 + q) ^ (rowB & 7)) * 8];
      }
#pragma unroll
      for (int mi = 0; mi < 4; ++mi)
#pragma unroll
        for (int ni = 0; ni < 4; ++ni)
          acc[mi][ni] = mfma32(af[mi], bf[ni], acc[mi][ni]);
    }
  }

  if (MODE == 2) {
    // acc[mi][ni][e]: token = m0+wy*64+mi*16+q*4+e, feat = n0+wx*64+ni*16+r.
    // -> vt2 tile (b, h, jt): V^T[hd=ni*16+r][key=mi*16+q*4+e], stored as
    // 16B chunks c2 = q + 4*(mi>>1) at slot c2^(hd&7), half (mi&1).
    const int bq = m0 >> 11;
    const int jt = ((m0 & 2047) >> 6) + wy;
    const int hh = (n0 >> 6) + wx;
    u16* vt_t = Cb + ((size_t)((bq * 16 + hh) * 32) + jt) * 4096;
#pragma unroll
    for (int mi = 0; mi < 4; ++mi)
#pragma unroll
      for (int ni = 0; ni < 4; ++ni) {
        short4v pk;
#pragma unroll
        for (int e = 0; e < 4; ++e) pk[e] = (short)f2bf(acc[mi][ni][e]);
        const int hd = ni * 16 + r;
        const int c2 = q + 4 * (mi >> 1);
        *(short4v*)&vt_t[hd * 64 + ((c2 ^ (r & 7)) * 8) + (mi & 1) * 4] = pk;
      }
    return;
  }

#pragma unroll
  for (int mi = 0; mi < 4; ++mi) {
    const int row = m0 + wy * 64 + mi * 16 + q * 4;
#pragma unroll
    for (int ni = 0; ni < 4; ++ni) {
      const int col = n0 + wx * 64 + ni * 16 + r;
#pragma unroll
      for (int e = 0; e < 4; ++e)
        Cb[(size_t)(row + e) * 1024 + col] = f2bf(acc[mi][ni][e]);
    }
  }
}

__global__ __launch_bounds__(256) void gemm_qkv(const u16* __restrict__ A,
                                                const u16* __restrict__ Wq,
                                                const u16* __restrict__ Wk,
                                                const u16* __restrict__ Wv,
                                                u16* __restrict__ Cq,
                                                u16* __restrict__ Ck,
                                                u16* __restrict__ Vt) {
  __shared__ u16 Asm[128 * 64];
  __shared__ u16 Wsm[128 * 64];
  const int z = blockIdx.z;
  if (z == 2)
    gemm_body<2>(A, Wv, Vt, blockIdx.x, blockIdx.y, Asm, Wsm);
  else
    gemm_body<0>(A, z ? Wk : Wq, z ? Ck : Cq, blockIdx.x, blockIdx.y, Asm, Wsm);
}

// ---------------------------------------------------------------------------
// Output GEMM v2 (f32 out): tile 128x64, grid (64,16) = 1024 blocks =
// 4 blocks/CU (R12; container-adjusted ~14 us better than the 512-block
// 128x128 -- the 2-barrier drain needs co-resident blocks, m114). 24 KB LDS.
// ---------------------------------------------------------------------------
__global__ __launch_bounds__(256) void gemm_out(const u16* __restrict__ A,
                                                const u16* __restrict__ W,
                                                float* __restrict__ C) {
  __shared__ u16 Asm[128 * 64];
  __shared__ u16 Wsm[64 * 64];
  const int t = threadIdx.x;
  const int w = t >> 6, l = t & 63;
  const int wy = w >> 1, wx = w & 1;
  const int q = l >> 4, r = l & 15;
  const int m0 = blockIdx.x * 128, n0 = blockIdx.y * 64;

  f32x4 acc[4][2] = {};

  for (int k0 = 0; k0 < 1024; k0 += 64) {
    __syncthreads();
#pragma unroll
    for (int i = 0; i < 4; ++i) {           // A: 1024 chunks
      const int c = t + i * 256;
      const int row = c >> 3, cl = c & 7;
      const int cg = cl ^ (row & 7);
      gl_lds16(A + (size_t)(m0 + row) * 1024 + k0 + cg * 8, &Asm[c * 8]);
    }
#pragma unroll
    for (int i = 0; i < 2; ++i) {           // W: 512 chunks
      const int c = t + i * 256;
      const int row = c >> 3, cl = c & 7;
      const int cg = cl ^ (row & 7);
      gl_lds16(W + (size_t)(n0 + row) * 1024 + k0 + cg * 8, &Wsm[c * 8]);
    }
    __syncthreads();
#pragma unroll
    for (int kf = 0; kf < 2; ++kf) {
      short8 af[4], bf[2];
#pragma unroll
      for (int mi = 0; mi < 4; ++mi) {
        const int rowA = wy * 64 + mi * 16 + r;
        af[mi] = *(const short8*)&Asm[rowA * 64 + ((kf * 4 + q) ^ (rowA & 7)) * 8];
      }
#pragma unroll
      for (int ni = 0; ni < 2; ++ni) {
        const int rowB = wx * 32 + ni * 16 + r;
        bf[ni] = *(const short8*)&Wsm[rowB * 64 + ((kf * 4 + q) ^ (rowB & 7)) * 8];
      }
#pragma unroll
      for (int mi = 0; mi < 4; ++mi)
#pragma unroll
        for (int ni = 0; ni < 2; ++ni)
          acc[mi][ni] = mfma32(af[mi], bf[ni], acc[mi][ni]);
    }
  }

#pragma unroll
  for (int mi = 0; mi < 4; ++mi) {
    const int row = m0 + wy * 64 + mi * 16 + q * 4;
#pragma unroll
    for (int ni = 0; ni < 2; ++ni) {
      const int col = n0 + wx * 32 + ni * 16 + r;
#pragma unroll
      for (int e = 0; e < 4; ++e)
        C[(size_t)(row + e) * 1024 + col] = acc[mi][ni][e];
    }
  }
}

// ---------------------------------------------------------------------------
// Flash attention v12 = v10 with V read DIRECTLY from L2 (no V LDS buffer).
// vt2 is stored in the exact MFMA A-frag layout (the LDS staging has been an
// identity copy since v5), so the 8 V fragments load straight to registers:
//   vv[np][ni2] = Vt[vgbase + jt*4096 + (np?b1:b0) + ni2*1024]   (16B each)
// Issued right after the iter-top barrier, BEFORE the K(jt+1) gl_lds
// prefetch: vmcnt is FIFO, so the compiler's wait for vv (vmcnt(4)) leaves
// the 4 younger K loads in flight -- the old manual protocol minus the
// second barrier. Removes per iter: 4 V gl_lds, 8 V ds_reads, 1 barrier
// (+vmcnt+sched fence); LDS 24->16 KB (cap 10 blocks/CU, grid cap 8).
// v7's lesson respected: only V moves to registers (+32 transient VGPR);
// K stays LDS-staged. Single-barrier protocol: the top __syncthreads'
// lgkmcnt(0) covers K-buffer read-before-overwrite, vmcnt(0) covers
// staging-complete-before-read. Bytes/math identical -> absmax unchanged.
// Retained: LPT dispatch, XCD pinning, register softmax via S^T trick,
// scale pre-folded into Wq, PV via mfma32, setprio on MFMA.
// ---------------------------------------------------------------------------
__global__ __launch_bounds__(128) void attn_v12(const u16* __restrict__ Qb,
                                                const u16* __restrict__ Kb,
                                                const u16* __restrict__ Vt,
                                                u16* __restrict__ Ob) {
  const int i = blockIdx.x;                      // 0..2047
  const int st = 31 - (i >> 6);                  // heavy q-tiles first (LPT)
  const int grp = (i & 7) + 8 * ((i >> 3) & 7);  // (b,h) group, XCD-pinned
  const int b = grp >> 4, h = grp & 15;
  const int t = threadIdx.x;
  const int w = t >> 6, l = t & 63;
  const int q = l >> 4, r = l & 15;

  __shared__ u16 Kd[2][4096];   // K double buffer (16 KB total LDS)

  const size_t kgbase = (size_t)(b * Sn) * Dn + h * 64;
  const u16* Vg = Vt + (size_t)((b * Hn + h) * 32) * 4096;

  const u16* kg[4];
#pragma unroll
  for (int ii = 0; ii < 4; ++ii) {
    const int c = t + ii * 128, row = c >> 3, cl = c & 7;
    kg[ii] = Kb + kgbase + (size_t)row * Dn + (cl ^ (row & 7)) * 8;
  }
  const int rx = r & 7;
  const int b0 = r * 64 + ((q ^ rx) * 8);
  const int b1 = r * 64 + (((4 + q) ^ rx) * 8);

  const int qb64 = st * 64;

  short8 Qf[2][2];
#pragma unroll
  for (int mi = 0; mi < 2; ++mi)
#pragma unroll
    for (int kf = 0; kf < 2; ++kf)
      Qf[mi][kf] = *(const short8*)(Qb +
          (size_t)(b * Sn + qb64 + w * 32 + mi * 16 + r) * Dn + h * 64 +
          kf * 32 + q * 8);

  f32x4 O[2][4] = {};
  float l_[2] = {0.f, 0.f};

  // prologue: stage K(0) -> Kd[0]
#pragma unroll
  for (int ii = 0; ii < 4; ++ii)
    gl_lds16(kg[ii], &Kd[0][(t + ii * 128) * 8]);

  const u16* kgt[4];
#pragma unroll
  for (int ii = 0; ii < 4; ++ii) kgt[ii] = kg[ii] + 64 * Dn;

  for (int jt = 0; jt <= st; ++jt) {
    __syncthreads();  // vmcnt(0)+lgkmcnt(0)+barrier: K(jt) staged; prev reads done

    // V(jt) fragments straight from L2, FIRST (vmcnt FIFO: the wait for
    // these before PV leaves the younger K(jt+1) gl_lds in flight)
    short8 vv[2][4];
    const u16* vtp = Vg + (size_t)jt * 4096;
#pragma unroll
    for (int np = 0; np < 2; ++np)
#pragma unroll
      for (int ni2 = 0; ni2 < 4; ++ni2)
        vv[np][ni2] = *(const short8*)(vtp + (np ? b1 : b0) + ni2 * 1024);

    // K(jt+1) prefetch into the other K buffer (spans the whole iteration)
    if (jt < st) {
      u16* kl = &Kd[(jt + 1) & 1][0];
#pragma unroll
      for (int ii = 0; ii < 4; ++ii) {
        gl_lds16(kgt[ii], kl + (t + ii * 128) * 8);
        kgt[ii] += 64 * Dn;
      }
    }

    const u16* KtA = &Kd[jt & 1][b0];
    const u16* KtB = &Kd[jt & 1][b1];

    short8 Kf[4][2];
#pragma unroll
    for (int ni = 0; ni < 4; ++ni) {
      Kf[ni][0] = *(const short8*)(KtA + ni * 1024);
      Kf[ni][1] = *(const short8*)(KtB + ni * 1024);
    }

    f32x4 S[2][4] = {};
    __builtin_amdgcn_s_setprio(1);
#pragma unroll
    for (int ni = 0; ni < 4; ++ni)
#pragma unroll
      for (int kf = 0; kf < 2; ++kf) {
        S[0][ni] = mfma32(Kf[ni][kf], Qf[0][kf], S[0][ni]);
        S[1][ni] = mfma32(Kf[ni][kf], Qf[1][kf], S[1][ni]);
      }
    __builtin_amdgcn_s_setprio(0);

    if (jt == st) {
#pragma unroll
      for (int mi = 0; mi < 2; ++mi) {
        const int qrow = w * 32 + mi * 16 + r;
#pragma unroll
        for (int ni = 0; ni < 4; ++ni) {
          const int key = ni * 16 + q * 4;
#pragma unroll
          for (int e = 0; e < 4; ++e)
            if (key + e > qrow) S[mi][ni][e] = -3.0e38f;
        }
      }
    }

    short8 P8[2][2];
#pragma unroll
    for (int mi = 0; mi < 2; ++mi)
#pragma unroll
      for (int np = 0; np < 2; ++np) {
        unsigned pw[4];
#pragma unroll
        for (int half = 0; half < 2; ++half) {
          const int ni = 2 * np + half;
          const float p0 = __builtin_amdgcn_exp2f(S[mi][ni][0]);
          const float p1 = __builtin_amdgcn_exp2f(S[mi][ni][1]);
          const float p2 = __builtin_amdgcn_exp2f(S[mi][ni][2]);
          const float p3 = __builtin_amdgcn_exp2f(S[mi][ni][3]);
          l_[mi] += (p0 + p1) + (p2 + p3);
          unsigned plo, phi;
          asm("v_cvt_pk_bf16_f32 %0, %1, %2" : "=v"(plo) : "v"(p0), "v"(p1));
          asm("v_cvt_pk_bf16_f32 %0, %1, %2" : "=v"(phi) : "v"(p2), "v"(p3));
          pw[half * 2] = plo;
          pw[half * 2 + 1] = phi;
        }
        const uint4v pk4 = {pw[0], pw[1], pw[2], pw[3]};
        P8[mi][np] = __builtin_bit_cast(short8, pk4);
      }

    // PV: V already in registers -- no barrier, no explicit vmcnt
    __builtin_amdgcn_s_setprio(1);
#pragma unroll
    for (int np = 0; np < 2; ++np)
#pragma unroll
      for (int ni2 = 0; ni2 < 4; ++ni2) {
        O[0][ni2] = mfma32(vv[np][ni2], P8[0][np], O[0][ni2]);
        O[1][ni2] = mfma32(vv[np][ni2], P8[1][np], O[1][ni2]);
      }
    __builtin_amdgcn_s_setprio(0);
  }

  // epilogue: reduce l over quads, scale, packed 8B stores
#pragma unroll
  for (int mi = 0; mi < 2; ++mi) {
    float s = l_[mi];
    s += __shfl_xor(s, 16, 64);
    s += __shfl_xor(s, 32, 64);
    const float rl = __builtin_amdgcn_rcpf(s);
#pragma unroll
    for (int ni2 = 0; ni2 < 4; ++ni2) {
      short4v o;
#pragma unroll
      for (int e = 0; e < 4; ++e) o[e] = (short)f2bf(O[mi][ni2][e] * rl);
      *(short4v*)(Ob + (size_t)(b * Sn + qb64 + w * 32 + mi * 16 + r) * Dn +
                  h * 64 + ni2 * 16 + q * 4) = o;
    }
  }
}

// ---------------------------------------------------------------------------
extern "C" void kernel_launch(void* const* d_in, const int* in_sizes, int n_in,
                              void* d_out, int out_size, void* d_ws, size_t ws_size,
                              hipStream_t stream) {
  const float* x  = (const float*)d_in[0];
  const float* wq = (const float*)d_in[1];
  const float* wk = (const float*)d_in[2];
  const float* wv = (const float*)d_in[3];
  const float* wo = (const float*)d_in[4];
  float* out = (float*)d_out;

  u16* xb  = (u16*)d_ws;            // 8M u16
  u16* wqb = xb + 8388608;
  u16* wkb = wqb + 1048576;
  u16* wvb = wkb + 1048576;
  u16* wob = wvb + 1048576;
  u16* qb  = wob + 1048576;         // 8M each
  u16* kb  = qb + 8388608;
  u16* vt2 = kb + 8388608;          // V^T tiles, pre-swizzled (MFMA layout)
  u16* aob = vt2 + 8388608;

  cast_all<<<12288, 256, 0, stream>>>(
      (const float4*)x, (const float4*)wq, (const float4*)wk,
      (const float4*)wv, (const float4*)wo, (ushort4*)xb, (ushort4*)wqb,
      (ushort4*)wkb, (ushort4*)wvb, (ushort4*)wob);

  gemm_qkv<<<dim3(64, 8, 3), 256, 0, stream>>>(xb, wqb, wkb, wvb, qb, kb, vt2);

  attn_v12<<<2048, 128, 0, stream>>>(qb, kb, vt2, aob);

  gemm_out<<<dim3(64, 16), 256, 0, stream>>>(aob, wob, out);
}